// Round 6
// baseline (385.132 us; speedup 1.0000x reference)
//
#include <hip/hip_runtime.h>
#include <stdint.h>

typedef unsigned short u16;
typedef __bf16 bf16x8 __attribute__((ext_vector_type(8)));
typedef float f32x4 __attribute__((ext_vector_type(4)));
typedef float f32x16 __attribute__((ext_vector_type(16)));
typedef u16 u16x8 __attribute__((ext_vector_type(8)));

#define MFMA16(a, b, c) __builtin_amdgcn_mfma_f32_16x16x32_bf16((a), (b), (c), 0, 0, 0)
#define MFMA32(a, b, c) __builtin_amdgcn_mfma_f32_32x32x16_bf16((a), (b), (c), 0, 0, 0)

__device__ __forceinline__ u16 f2bf(float f) {
  union { float f; uint32_t u; } v; v.f = f;
  uint32_t u = v.u;
  return (u16)((u + 0x7FFFu + ((u >> 16) & 1u)) >> 16);
}

__device__ __forceinline__ uint32_t pk2(float a, float b) {
  union { __bf16 h[2]; uint32_t u; } v;
  v.h[0] = (__bf16)a; v.h[1] = (__bf16)b;
  return v.u;
}

// async global(16B/lane) -> LDS, wave-uniform dest base + lane*16
__device__ __forceinline__ void gload_lds16(const u16* g, u16* l) {
  __builtin_amdgcn_global_load_lds((const __attribute__((address_space(1))) void*)g,
                                   (__attribute__((address_space(3))) void*)l, 16, 0, 0);
}

// ---------------------------------------------------------------------------
// Elementwise fp32 -> bf16 (x), vectorized
// ---------------------------------------------------------------------------
__global__ void cvt_bf16(const float* __restrict__ in, u16* __restrict__ out, int n4) {
  int i = blockIdx.x * 256 + threadIdx.x;
  if (i < n4) {
    float4 v = ((const float4*)in)[i];
    ushort4 o;
    o.x = f2bf(v.x); o.y = f2bf(v.y); o.z = f2bf(v.z); o.w = f2bf(v.w);
    ((ushort4*)out)[i] = o;
  }
}

// ---------------------------------------------------------------------------
// Transpose + convert fp32 (R x C) -> bf16 (C x R), with scale
// ---------------------------------------------------------------------------
__global__ __launch_bounds__(256) void transpose_cvt(const float* __restrict__ in,
                                                     u16* __restrict__ out,
                                                     int R, int C, float scale) {
  __shared__ float t32[32][33];
  int c0 = blockIdx.x * 32, r0 = blockIdx.y * 32;
  int tx = threadIdx.x & 31, ty = threadIdx.x >> 5;  // 32 x 8
  #pragma unroll
  for (int i = 0; i < 32; i += 8)
    t32[ty + i][tx] = in[(size_t)(r0 + ty + i) * C + c0 + tx] * scale;
  __syncthreads();
  #pragma unroll
  for (int i = 0; i < 32; i += 8)
    out[(size_t)(c0 + ty + i) * R + r0 + tx] = f2bf(t32[tx][ty + i]);
}

// ---------------------------------------------------------------------------
// C(M x N) = A(M x K) @ Bt(N x K)^T   — 128x128 tile, BK=32, 4 waves
// FOUT: 0 = bf16 row-major; 1 = f32 row-major; 2 = bf16 transposed into
//       Vt (b,h,d,t) layout (M=8192 rows are b*1024+t, N cols are h*256+d).
// ---------------------------------------------------------------------------
template<int FOUT>
__global__ __launch_bounds__(256, 2) void gemm_bt(const u16* __restrict__ A,
                                                  const u16* __restrict__ Bt,
                                                  void* __restrict__ Cout,
                                                  int M, int N, int K,
                                                  int lda, int ldb, int ldc) {
  __shared__ __attribute__((aligned(16))) u16 As[128 * 32];
  __shared__ __attribute__((aligned(16))) u16 Bs[128 * 32];
  const int tid = threadIdx.x;
  const int lane = tid & 63;
  const int w = tid >> 6;
  const int wr = w >> 1, wc = w & 1;
  const int row0 = blockIdx.y * 128, col0 = blockIdx.x * 128;
  const int rr = lane & 15, kg = lane >> 4;

  f32x4 acc[4][4];
  const f32x4 fz = {0.f, 0.f, 0.f, 0.f};
  #pragma unroll
  for (int m = 0; m < 4; ++m)
    #pragma unroll
    for (int n = 0; n < 4; ++n) acc[m][n] = fz;

  for (int k0 = 0; k0 < K; k0 += 32) {
    #pragma unroll
    for (int c = 0; c < 2; ++c) {
      int Lb = c * 256 + w * 64;
      int L = Lb + lane;
      int r = L >> 2, cc = L & 3;
      gload_lds16(&A[(size_t)(row0 + r) * lda + k0 + cc * 8], &As[Lb << 3]);
      gload_lds16(&Bt[(size_t)(col0 + r) * ldb + k0 + cc * 8], &Bs[Lb << 3]);
    }
    __syncthreads();
    bf16x8 af[4], bfr[4];
    #pragma unroll
    for (int m = 0; m < 4; ++m)
      af[m] = *(const bf16x8*)&As[(wr * 64 + m * 16 + rr) * 32 + kg * 8];
    #pragma unroll
    for (int n = 0; n < 4; ++n)
      bfr[n] = *(const bf16x8*)&Bs[(wc * 64 + n * 16 + rr) * 32 + kg * 8];
    #pragma unroll
    for (int m = 0; m < 4; ++m)
      #pragma unroll
      for (int n = 0; n < 4; ++n)
        acc[m][n] = MFMA16(af[m], bfr[n], acc[m][n]);
    __syncthreads();
  }

  #pragma unroll
  for (int m = 0; m < 4; ++m)
    #pragma unroll
    for (int n = 0; n < 4; ++n) {
      int r = row0 + wr * 64 + m * 16 + kg * 4;
      int c = col0 + wc * 64 + n * 16 + rr;
      if (FOUT == 2) {
        // transposed store into Vt (b,h,d,t): j (row dir) is contiguous in t
        int bb = r >> 10, tt = r & 1023;
        int hh = c >> 8, dd = c & 255;
        union { u16 h4[4]; uint2 u2; } o4;
        #pragma unroll
        for (int j = 0; j < 4; ++j) o4.h4[j] = f2bf(acc[m][n][j]);
        *(uint2*)&((u16*)Cout)[(size_t)(bb * 8 + hh) * 262144 + (size_t)dd * 1024 + tt] = o4.u2;
      } else {
        #pragma unroll
        for (int j = 0; j < 4; ++j) {
          if (FOUT == 0)
            ((u16*)Cout)[(size_t)(r + j) * ldc + c] = f2bf(acc[m][n][j]);
          else
            ((float*)Cout)[(size_t)(r + j) * ldc + c] = acc[m][n][j];
        }
      }
    }
}

// ---------------------------------------------------------------------------
// 64x128-tile GEMM (for M-heavy, small-N out-projection): grid (N/128, M/64)
// ---------------------------------------------------------------------------
template<int FOUT>
__global__ __launch_bounds__(256, 2) void gemm_bt64(const u16* __restrict__ A,
                                                    const u16* __restrict__ Bt,
                                                    void* __restrict__ Cout,
                                                    int M, int N, int K,
                                                    int lda, int ldb, int ldc) {
  __shared__ __attribute__((aligned(16))) u16 As[64 * 32];
  __shared__ __attribute__((aligned(16))) u16 Bs[128 * 32];
  const int tid = threadIdx.x;
  const int lane = tid & 63;
  const int w = tid >> 6;
  const int row0 = blockIdx.y * 64, col0 = blockIdx.x * 128;
  const int rr = lane & 15, kg = lane >> 4;

  f32x4 acc[4][2];
  const f32x4 fz = {0.f, 0.f, 0.f, 0.f};
  #pragma unroll
  for (int m = 0; m < 4; ++m)
    #pragma unroll
    for (int n = 0; n < 2; ++n) acc[m][n] = fz;

  for (int k0 = 0; k0 < K; k0 += 32) {
    {  // A: 256 chunks, all 4 waves
      int Lb = w * 64;
      int L = Lb + lane;
      int r = L >> 2, cc = L & 3;
      gload_lds16(&A[(size_t)(row0 + r) * lda + k0 + cc * 8], &As[Lb << 3]);
    }
    #pragma unroll
    for (int c = 0; c < 2; ++c) {  // B: 512 chunks
      int Lb = c * 256 + w * 64;
      int L = Lb + lane;
      int r = L >> 2, cc = L & 3;
      gload_lds16(&Bt[(size_t)(col0 + r) * ldb + k0 + cc * 8], &Bs[Lb << 3]);
    }
    __syncthreads();
    bf16x8 af[4], bfr[2];
    #pragma unroll
    for (int m = 0; m < 4; ++m)
      af[m] = *(const bf16x8*)&As[(m * 16 + rr) * 32 + kg * 8];
    #pragma unroll
    for (int n = 0; n < 2; ++n)
      bfr[n] = *(const bf16x8*)&Bs[(w * 32 + n * 16 + rr) * 32 + kg * 8];
    #pragma unroll
    for (int m = 0; m < 4; ++m)
      #pragma unroll
      for (int n = 0; n < 2; ++n)
        acc[m][n] = MFMA16(af[m], bfr[n], acc[m][n]);
    __syncthreads();
  }

  #pragma unroll
  for (int m = 0; m < 4; ++m)
    #pragma unroll
    for (int n = 0; n < 2; ++n) {
      int r = row0 + m * 16 + kg * 4;
      int c = col0 + w * 32 + n * 16 + rr;
      #pragma unroll
      for (int j = 0; j < 4; ++j) {
        if (FOUT == 0)
          ((u16*)Cout)[(size_t)(r + j) * ldc + c] = f2bf(acc[m][n][j]);
        else
          ((float*)Cout)[(size_t)(r + j) * ldc + c] = acc[m][n][j];
      }
    }
}

// ---------------------------------------------------------------------------
// Flash attention, 32x32x16 MFMA, swapped operands (q = lane&31 everywhere).
// 8 waves x 32 q-rows = 256 q-rows per block; KVBLK=64; K/V double-buffered.
// Q register-resident (qf[16], loaded once). amdgpu_waves_per_eu(2,2) forces
// the 256-VGPR budget (2 waves/SIMD) so the ~250-reg peak does NOT spill —
// R4's spill was the compiler's 128-reg heuristic cap, not true demand.
// LDS: 2*32K (K) + 2*32K (V) = 128 KB -> 1 block/CU.
// ---------------------------------------------------------------------------
__global__ __launch_bounds__(512) __attribute__((amdgpu_waves_per_eu(2, 2)))
void attn_kernel(const u16* __restrict__ Q,
                 const u16* __restrict__ Kg,
                 const u16* __restrict__ Vt,
                 u16* __restrict__ O) {
  __shared__ __attribute__((aligned(16))) u16 smem[65536];
  u16* Ks = smem;              // [2][64][256], chunk-XOR swizzled
  u16* Vs = smem + 32768;      // [2][256][64], chunk-XOR swizzled
  const int tid = threadIdx.x;
  const int lane = tid & 63;
  const int w = tid >> 6;
  const int ql = lane & 31, hi = lane >> 5;
  const int bid = blockIdx.x;
  const int swz = (bid & 7) * 32 + (bid >> 3);  // XCD-contiguous, bijective (256)
  const int bh = swz >> 2;
  const int b = bh >> 3, h = bh & 7;
  const int q0 = (swz & 3) * 256;
  const u16* Qb = Q + (size_t)b * 1024 * 2048 + (size_t)h * 256;
  const u16* Kb = Kg + (size_t)b * 1024 * 2048 + (size_t)h * 256;
  const u16* Vb = Vt + (size_t)bh * 262144;  // [256][1024]
  u16* Ob = O + (size_t)b * 1024 * 2048 + (size_t)h * 256;
  const int qrow = q0 + w * 32 + ql;

  auto stage_kv = [&](int sb, int s0i) {
    u16* Kd = Ks + sb * 16384;
    u16* Vd = Vs + sb * 16384;
    #pragma unroll
    for (int c = 0; c < 4; ++c) {
      int Lb = (c * 8 + w) * 64;
      int L = Lb + lane;
      int r = L >> 5, cc = L & 31;        // K: row 0..63, chunk 0..31
      gload_lds16(&Kb[(size_t)(s0i + r) * 2048 + ((cc ^ (r & 7)) << 3)], &Kd[Lb << 3]);
      int rv = L >> 3, cv = L & 7;        // V: d-row 0..255, chunk 0..7
      gload_lds16(&Vb[(size_t)rv * 1024 + s0i + ((cv ^ (rv & 7)) << 3)], &Vd[Lb << 3]);
    }
  };

  stage_kv(0, 0);

  // Q B-frags, register-resident: q=lane&31, k(d) = kk*16 + hi*8 + j
  bf16x8 qf[16];
  {
    const u16* qp = Qb + (size_t)qrow * 2048 + hi * 8;
    #pragma unroll
    for (int kk = 0; kk < 16; ++kk) qf[kk] = *(const bf16x8*)&qp[kk * 16];
  }

  f32x16 oacc[8];
  #pragma unroll
  for (int db = 0; db < 8; ++db)
    #pragma unroll
    for (int i = 0; i < 16; ++i) oacc[db][i] = 0.f;
  float mrow = -1e30f, lrow = 0.f;

  __syncthreads();  // drains vmcnt: K/V tile 0 staged

  int buf = 0;
  for (int t = 0; t < 16; ++t) {
    if (t < 15) stage_kv(buf ^ 1, (t + 1) * 64);

    // S^T[64 s][32 q] = mfma(K, Q) over d
    const u16* Kd = Ks + buf * 16384;
    f32x16 s0, s1;
    #pragma unroll
    for (int i = 0; i < 16; ++i) { s0[i] = 0.f; s1[i] = 0.f; }
    __builtin_amdgcn_s_setprio(1);
    #pragma unroll
    for (int kk = 0; kk < 16; ++kk) {
      int ck = kk * 2 + hi;
      int r0 = ql;
      bf16x8 k0 = *(const bf16x8*)&Kd[r0 * 256 + ((ck ^ (r0 & 7)) << 3)];
      s0 = MFMA32(k0, qf[kk], s0);
      int r1 = 32 + ql;
      bf16x8 k1 = *(const bf16x8*)&Kd[r1 * 256 + ((ck ^ (r1 & 7)) << 3)];
      s1 = MFMA32(k1, qf[kk], s1);
    }
    __builtin_amdgcn_s_setprio(0);

    // in-register online softmax (lane owns q = ql; lane^32 has other s-half)
    float vmax = s0[0];
    #pragma unroll
    for (int i = 1; i < 16; ++i) vmax = fmaxf(vmax, s0[i]);
    #pragma unroll
    for (int i = 0; i < 16; ++i) vmax = fmaxf(vmax, s1[i]);
    vmax = fmaxf(vmax, __shfl_xor(vmax, 32, 64));
    if (__any(vmax > mrow + 8.f)) {  // T13 defer-max
      float mn = fmaxf(mrow, vmax);
      float resc = __expf(mrow - mn);
      mrow = mn;
      lrow *= resc;
      #pragma unroll
      for (int db = 0; db < 8; ++db)
        #pragma unroll
        for (int i = 0; i < 16; ++i) oacc[db][i] *= resc;
    }
    float sum = 0.f;
    uint32_t pk[16], xch[16];
    #pragma unroll
    for (int g = 0; g < 4; ++g) {
      float e0 = __expf(s0[g * 4 + 0] - mrow), e1 = __expf(s0[g * 4 + 1] - mrow);
      float e2 = __expf(s0[g * 4 + 2] - mrow), e3 = __expf(s0[g * 4 + 3] - mrow);
      sum += (e0 + e1) + (e2 + e3);
      pk[g * 2 + 0] = pk2(e0, e1);
      pk[g * 2 + 1] = pk2(e2, e3);
    }
    #pragma unroll
    for (int g = 0; g < 4; ++g) {
      float e0 = __expf(s1[g * 4 + 0] - mrow), e1 = __expf(s1[g * 4 + 1] - mrow);
      float e2 = __expf(s1[g * 4 + 2] - mrow), e3 = __expf(s1[g * 4 + 3] - mrow);
      sum += (e0 + e1) + (e2 + e3);
      pk[8 + g * 2 + 0] = pk2(e0, e1);
      pk[8 + g * 2 + 1] = pk2(e2, e3);
    }
    sum += __shfl_xor(sum, 32, 64);
    lrow += sum;
    #pragma unroll
    for (int i = 0; i < 16; ++i) xch[i] = __shfl_xor(pk[i], 32, 64);

    // O^T += mfma(Vt, P): P B-frag built from pk/xch (q=ql, k(s)=kk*16+hi*8+j)
    const u16* Vd = Vs + buf * 16384;
    #pragma unroll
    for (int kk = 0; kk < 4; ++kk) {
      const int sb8 = (kk >> 1) * 8;
      const int ge = (kk & 1) * 2, go = ge + 1;
      union { uint32_t u[4]; bf16x8 v; } pf;
      pf.u[0] = hi ? xch[sb8 + go * 2 + 0] : pk[sb8 + ge * 2 + 0];
      pf.u[1] = hi ? xch[sb8 + go * 2 + 1] : pk[sb8 + ge * 2 + 1];
      pf.u[2] = hi ? pk[sb8 + go * 2 + 0] : xch[sb8 + ge * 2 + 0];
      pf.u[3] = hi ? pk[sb8 + go * 2 + 1] : xch[sb8 + ge * 2 + 1];
      int cv = kk * 2 + hi;
      __builtin_amdgcn_s_setprio(1);
      #pragma unroll
      for (int db = 0; db < 8; ++db) {
        int rv = db * 32 + ql;
        bf16x8 vf = *(const bf16x8*)&Vd[rv * 64 + ((cv ^ (rv & 7)) << 3)];
        oacc[db] = MFMA32(vf, pf.v, oacc[db]);
      }
      __builtin_amdgcn_s_setprio(0);
    }

    __syncthreads();  // drains vmcnt(0): next K/V staged; bufs safe to swap
    buf ^= 1;
  }

  // normalize + store: lane holds q=qrow, d = db*32 + m2*8 + hi*4 + i
  float inv = 1.0f / lrow;
  #pragma unroll
  for (int db = 0; db < 8; ++db)
    #pragma unroll
    for (int m2 = 0; m2 < 4; ++m2) {
      union { u16 h[4]; uint2 u2; } o4;
      #pragma unroll
      for (int i = 0; i < 4; ++i) o4.h[i] = f2bf(oacc[db][m2 * 4 + i] * inv);
      *(uint2*)&Ob[(size_t)qrow * 2048 + db * 32 + m2 * 8 + hi * 4] = o4.u2;
    }
}

// ---------------------------------------------------------------------------
extern "C" void kernel_launch(void* const* d_in, const int* in_sizes, int n_in,
                              void* d_out, int out_size, void* d_ws, size_t ws_size,
                              hipStream_t stream) {
  const float* x  = (const float*)d_in[0];
  const float* Wq = (const float*)d_in[1];
  const float* Wk = (const float*)d_in[2];
  const float* Wv = (const float*)d_in[3];
  const float* Wu = (const float*)d_in[4];

  // workspace layout (u16 units)
  u16* xb  = (u16*)d_ws;                 // 8192*256
  u16* WtQ = xb  + 8192 * 256;           // 2048*256
  u16* WtK = WtQ + 2048 * 256;
  u16* WtV = WtK + 2048 * 256;
  u16* Wut = WtV + 2048 * 256;           // 256*2048
  u16* Qm  = Wut + 2048 * 256;           // 8192*2048 each below
  u16* Km  = Qm  + (size_t)8192 * 2048;
  u16* Vtm = Km  + (size_t)8192 * 2048;  // V written TRANSPOSED by gemm_bt<2>
  u16* Om  = Vtm + (size_t)8192 * 2048;

  const float inv4 = 0.25f;  // 256^(-1/4)

  cvt_bf16<<<2048, 256, 0, stream>>>(x, xb, 8192 * 256 / 4);
  transpose_cvt<<<dim3(64, 8), 256, 0, stream>>>(Wq, WtQ, 256, 2048, inv4);
  transpose_cvt<<<dim3(64, 8), 256, 0, stream>>>(Wk, WtK, 256, 2048, inv4);
  transpose_cvt<<<dim3(64, 8), 256, 0, stream>>>(Wv, WtV, 256, 2048, 1.0f);
  transpose_cvt<<<dim3(8, 64), 256, 0, stream>>>(Wu, Wut, 2048, 256, 1.0f);

  gemm_bt<0><<<dim3(16, 64), 256, 0, stream>>>(xb, WtQ, Qm, 8192, 2048, 256, 256, 256, 2048);
  gemm_bt<0><<<dim3(16, 64), 256, 0, stream>>>(xb, WtK, Km, 8192, 2048, 256, 256, 256, 2048);
  gemm_bt<2><<<dim3(16, 64), 256, 0, stream>>>(xb, WtV, Vtm, 8192, 2048, 256, 256, 256, 0);

  attn_kernel<<<256, 512, 0, stream>>>(Qm, Km, Vtm, Om);

  gemm_bt64<1><<<dim3(2, 128), 256, 0, stream>>>(Om, Wut, d_out, 8192, 256, 2048, 2048, 2048, 256);
}

// Round 7
// 215.139 us; speedup vs baseline: 1.7902x; 1.7902x over previous
//
#include <hip/hip_runtime.h>
#include <stdint.h>

typedef unsigned short u16;
typedef __bf16 bf16x8 __attribute__((ext_vector_type(8)));
typedef float f32x4 __attribute__((ext_vector_type(4)));
typedef u16 u16x8 __attribute__((ext_vector_type(8)));

#define MFMA16(a, b, c) __builtin_amdgcn_mfma_f32_16x16x32_bf16((a), (b), (c), 0, 0, 0)

__device__ __forceinline__ u16 f2bf(float f) {
  union { float f; uint32_t u; } v; v.f = f;
  uint32_t u = v.u;
  return (u16)((u + 0x7FFFu + ((u >> 16) & 1u)) >> 16);
}

__device__ __forceinline__ uint32_t pk2(float a, float b) {
  union { __bf16 h[2]; uint32_t u; } v;
  v.h[0] = (__bf16)a; v.h[1] = (__bf16)b;
  return v.u;
}

// async global(16B/lane) -> LDS, wave-uniform dest base + lane*16
__device__ __forceinline__ void gload_lds16(const u16* g, u16* l) {
  __builtin_amdgcn_global_load_lds((const __attribute__((address_space(1))) void*)g,
                                   (__attribute__((address_space(3))) void*)l, 16, 0, 0);
}

// ---------------------------------------------------------------------------
// Elementwise fp32 -> bf16 (x), vectorized
// ---------------------------------------------------------------------------
__global__ void cvt_bf16(const float* __restrict__ in, u16* __restrict__ out, int n4) {
  int i = blockIdx.x * 256 + threadIdx.x;
  if (i < n4) {
    float4 v = ((const float4*)in)[i];
    ushort4 o;
    o.x = f2bf(v.x); o.y = f2bf(v.y); o.z = f2bf(v.z); o.w = f2bf(v.w);
    ((ushort4*)out)[i] = o;
  }
}

// ---------------------------------------------------------------------------
// Transpose + convert fp32 (R x C) -> bf16 (C x R), with scale
// ---------------------------------------------------------------------------
__global__ __launch_bounds__(256) void transpose_cvt(const float* __restrict__ in,
                                                     u16* __restrict__ out,
                                                     int R, int C, float scale) {
  __shared__ float t32[32][33];
  int c0 = blockIdx.x * 32, r0 = blockIdx.y * 32;
  int tx = threadIdx.x & 31, ty = threadIdx.x >> 5;  // 32 x 8
  #pragma unroll
  for (int i = 0; i < 32; i += 8)
    t32[ty + i][tx] = in[(size_t)(r0 + ty + i) * C + c0 + tx] * scale;
  __syncthreads();
  #pragma unroll
  for (int i = 0; i < 32; i += 8)
    out[(size_t)(c0 + ty + i) * R + r0 + tx] = f2bf(t32[tx][ty + i]);
}

// ---------------------------------------------------------------------------
// C(M x N) = A(M x K) @ Bt(N x K)^T   — 128x128 tile, BK=32, 4 waves
// FOUT: 0 = bf16 row-major; 1 = f32 row-major; 2 = bf16 transposed into
//       Vt (b,h,d,t) layout (M=8192 rows are b*1024+t, N cols are h*256+d).
// ---------------------------------------------------------------------------
template<int FOUT>
__global__ __launch_bounds__(256, 2) void gemm_bt(const u16* __restrict__ A,
                                                  const u16* __restrict__ Bt,
                                                  void* __restrict__ Cout,
                                                  int M, int N, int K,
                                                  int lda, int ldb, int ldc) {
  __shared__ __attribute__((aligned(16))) u16 As[128 * 32];
  __shared__ __attribute__((aligned(16))) u16 Bs[128 * 32];
  const int tid = threadIdx.x;
  const int lane = tid & 63;
  const int w = tid >> 6;
  const int wr = w >> 1, wc = w & 1;
  const int row0 = blockIdx.y * 128, col0 = blockIdx.x * 128;
  const int rr = lane & 15, kg = lane >> 4;

  f32x4 acc[4][4];
  const f32x4 fz = {0.f, 0.f, 0.f, 0.f};
  #pragma unroll
  for (int m = 0; m < 4; ++m)
    #pragma unroll
    for (int n = 0; n < 4; ++n) acc[m][n] = fz;

  for (int k0 = 0; k0 < K; k0 += 32) {
    #pragma unroll
    for (int c = 0; c < 2; ++c) {
      int Lb = c * 256 + w * 64;
      int L = Lb + lane;
      int r = L >> 2, cc = L & 3;
      gload_lds16(&A[(size_t)(row0 + r) * lda + k0 + cc * 8], &As[Lb << 3]);
      gload_lds16(&Bt[(size_t)(col0 + r) * ldb + k0 + cc * 8], &Bs[Lb << 3]);
    }
    __syncthreads();
    bf16x8 af[4], bfr[4];
    #pragma unroll
    for (int m = 0; m < 4; ++m)
      af[m] = *(const bf16x8*)&As[(wr * 64 + m * 16 + rr) * 32 + kg * 8];
    #pragma unroll
    for (int n = 0; n < 4; ++n)
      bfr[n] = *(const bf16x8*)&Bs[(wc * 64 + n * 16 + rr) * 32 + kg * 8];
    #pragma unroll
    for (int m = 0; m < 4; ++m)
      #pragma unroll
      for (int n = 0; n < 4; ++n)
        acc[m][n] = MFMA16(af[m], bfr[n], acc[m][n]);
    __syncthreads();
  }

  #pragma unroll
  for (int m = 0; m < 4; ++m)
    #pragma unroll
    for (int n = 0; n < 4; ++n) {
      int r = row0 + wr * 64 + m * 16 + kg * 4;
      int c = col0 + wc * 64 + n * 16 + rr;
      if (FOUT == 2) {
        // transposed store into Vt (b,h,d,t): j (row dir) is contiguous in t
        int bb = r >> 10, tt = r & 1023;
        int hh = c >> 8, dd = c & 255;
        union { u16 h4[4]; uint2 u2; } o4;
        #pragma unroll
        for (int j = 0; j < 4; ++j) o4.h4[j] = f2bf(acc[m][n][j]);
        *(uint2*)&((u16*)Cout)[(size_t)(bb * 8 + hh) * 262144 + (size_t)dd * 1024 + tt] = o4.u2;
      } else {
        #pragma unroll
        for (int j = 0; j < 4; ++j) {
          if (FOUT == 0)
            ((u16*)Cout)[(size_t)(r + j) * ldc + c] = f2bf(acc[m][n][j]);
          else
            ((float*)Cout)[(size_t)(r + j) * ldc + c] = acc[m][n][j];
        }
      }
    }
}

// ---------------------------------------------------------------------------
// 64x128-tile GEMM (for M-heavy, small-N out-projection): grid (N/128, M/64)
// ---------------------------------------------------------------------------
template<int FOUT>
__global__ __launch_bounds__(256, 2) void gemm_bt64(const u16* __restrict__ A,
                                                    const u16* __restrict__ Bt,
                                                    void* __restrict__ Cout,
                                                    int M, int N, int K,
                                                    int lda, int ldb, int ldc) {
  __shared__ __attribute__((aligned(16))) u16 As[64 * 32];
  __shared__ __attribute__((aligned(16))) u16 Bs[128 * 32];
  const int tid = threadIdx.x;
  const int lane = tid & 63;
  const int w = tid >> 6;
  const int row0 = blockIdx.y * 64, col0 = blockIdx.x * 128;
  const int rr = lane & 15, kg = lane >> 4;

  f32x4 acc[4][2];
  const f32x4 fz = {0.f, 0.f, 0.f, 0.f};
  #pragma unroll
  for (int m = 0; m < 4; ++m)
    #pragma unroll
    for (int n = 0; n < 2; ++n) acc[m][n] = fz;

  for (int k0 = 0; k0 < K; k0 += 32) {
    {  // A: 256 chunks, all 4 waves
      int Lb = w * 64;
      int L = Lb + lane;
      int r = L >> 2, cc = L & 3;
      gload_lds16(&A[(size_t)(row0 + r) * lda + k0 + cc * 8], &As[Lb << 3]);
    }
    #pragma unroll
    for (int c = 0; c < 2; ++c) {  // B: 512 chunks
      int Lb = c * 256 + w * 64;
      int L = Lb + lane;
      int r = L >> 2, cc = L & 3;
      gload_lds16(&Bt[(size_t)(col0 + r) * ldb + k0 + cc * 8], &Bs[Lb << 3]);
    }
    __syncthreads();
    bf16x8 af[4], bfr[2];
    #pragma unroll
    for (int m = 0; m < 4; ++m)
      af[m] = *(const bf16x8*)&As[(m * 16 + rr) * 32 + kg * 8];
    #pragma unroll
    for (int n = 0; n < 2; ++n)
      bfr[n] = *(const bf16x8*)&Bs[(w * 32 + n * 16 + rr) * 32 + kg * 8];
    #pragma unroll
    for (int m = 0; m < 4; ++m)
      #pragma unroll
      for (int n = 0; n < 2; ++n)
        acc[m][n] = MFMA16(af[m], bfr[n], acc[m][n]);
    __syncthreads();
  }

  #pragma unroll
  for (int m = 0; m < 4; ++m)
    #pragma unroll
    for (int n = 0; n < 2; ++n) {
      int r = row0 + m * 16 + kg * 4;
      int c = col0 + w * 32 + n * 16 + rr;
      #pragma unroll
      for (int j = 0; j < 4; ++j) {
        if (FOUT == 0)
          ((u16*)Cout)[(size_t)(r + j) * ldc + c] = f2bf(acc[m][n][j]);
        else
          ((float*)Cout)[(size_t)(r + j) * ldc + c] = acc[m][n][j];
      }
    }
}

// ---------------------------------------------------------------------------
// Flash attention, 16x16x32 MFMA, swapped operands.
// 8 waves x 16 q-rows = 128 q-rows per block; KVBLK=64; K/V double-buffered.
// q = lane&15 everywhere (A=K / A=Vt, B=Q / B=P). Lane holds s = n4*16+kg*4+j
// of S^T -> softmax = 15-op chain + 2 shfl_xor. P redistributed to PV B-frags
// by a 4-lane butterfly (12 shfl_xor + static selects per s-half). Q resident
// in 32 VGPRs. State: oacc 64 + qf 32 + sacc 16 -> no spill at 128-arch cap.
// LDS: 2*32K (K) + 2*32K (V) = 128 KB -> 1 block/CU.
// ---------------------------------------------------------------------------
__global__ __launch_bounds__(512) void attn_kernel(const u16* __restrict__ Q,
                                                   const u16* __restrict__ Kg,
                                                   const u16* __restrict__ Vt,
                                                   u16* __restrict__ O) {
  __shared__ __attribute__((aligned(16))) u16 smem[65536];
  u16* Ks = smem;              // [2][64][256], chunk-XOR swizzled
  u16* Vs = smem + 32768;      // [2][256][64], chunk-XOR swizzled
  const int tid = threadIdx.x;
  const int lane = tid & 63;
  const int w = tid >> 6;
  const int rr = lane & 15, kg = lane >> 4;
  const int bid = blockIdx.x;
  const int swz = (bid & 7) * 64 + (bid >> 3);  // XCD-contiguous, bijective (512)
  const int bh = swz >> 3;
  const int b = bh >> 3, h = bh & 7;
  const int q0 = (swz & 7) * 128;
  const u16* Qb = Q + (size_t)b * 1024 * 2048 + (size_t)h * 256;
  const u16* Kb = Kg + (size_t)b * 1024 * 2048 + (size_t)h * 256;
  const u16* Vb = Vt + (size_t)bh * 262144;  // [256][1024]
  u16* Ob = O + (size_t)b * 1024 * 2048 + (size_t)h * 256;
  const int qrow = q0 + w * 16 + rr;

  auto stage_kv = [&](int sb, int s0i) {
    u16* Kd = Ks + sb * 16384;
    u16* Vd = Vs + sb * 16384;
    #pragma unroll
    for (int c = 0; c < 4; ++c) {
      int Lb = (c * 8 + w) * 64;
      int L = Lb + lane;
      int r = L >> 5, cc = L & 31;        // K: row 0..63, chunk 0..31
      gload_lds16(&Kb[(size_t)(s0i + r) * 2048 + ((cc ^ (r & 7)) << 3)], &Kd[Lb << 3]);
      int rv = L >> 3, cv = L & 7;        // V: d-row 0..255, chunk 0..7
      gload_lds16(&Vb[(size_t)rv * 1024 + s0i + ((cv ^ (rv & 7)) << 3)], &Vd[Lb << 3]);
    }
  };

  stage_kv(0, 0);

  // Q B-frags (q = rr, k(d) = kk*32 + kg*8 + j), register-resident: 32 VGPRs
  bf16x8 qf[8];
  {
    const u16* qp = Qb + (size_t)qrow * 2048;
    #pragma unroll
    for (int kk = 0; kk < 8; ++kk) qf[kk] = *(const bf16x8*)&qp[kk * 32 + kg * 8];
  }

  const f32x4 fz = {0.f, 0.f, 0.f, 0.f};
  f32x4 oacc[16];   // O^T[d][q]: row d = dt*16 + kg*4 + i, col q = rr
  #pragma unroll
  for (int dt = 0; dt < 16; ++dt) oacc[dt] = fz;
  float mrow = -1e30f, lrow = 0.f;

  __syncthreads();  // drains vmcnt: K/V tile 0 staged, qf loaded

  int buf = 0;
  for (int t = 0; t < 16; ++t) {
    if (t < 15) stage_kv(buf ^ 1, (t + 1) * 64);

    // S^T[64 s][16 q] = mfma(K, Q): sacc[n4] rows s = n4*16 + kg*4 + j
    const u16* Kd = Ks + buf * 16384;
    f32x4 sacc[4];
    #pragma unroll
    for (int n4 = 0; n4 < 4; ++n4) sacc[n4] = fz;
    __builtin_amdgcn_s_setprio(1);
    #pragma unroll
    for (int kk = 0; kk < 8; ++kk) {
      #pragma unroll
      for (int n4 = 0; n4 < 4; ++n4) {
        int row = n4 * 16 + rr;
        int ck = kk * 4 + kg;
        bf16x8 kf = *(const bf16x8*)&Kd[row * 256 + ((ck ^ (row & 7)) << 3)];
        sacc[n4] = MFMA16(kf, qf[kk], sacc[n4]);
      }
    }
    __builtin_amdgcn_s_setprio(0);

    // online softmax: lane has 16 s for q=rr; reduce over kg lanes (xor 16,32)
    float vmax = sacc[0][0];
    #pragma unroll
    for (int n4 = 0; n4 < 4; ++n4)
      #pragma unroll
      for (int j = 0; j < 4; ++j) vmax = fmaxf(vmax, sacc[n4][j]);
    vmax = fmaxf(vmax, __shfl_xor(vmax, 16, 64));
    vmax = fmaxf(vmax, __shfl_xor(vmax, 32, 64));
    if (__any(vmax > mrow + 8.f)) {  // T13 defer-max
      float mn = fmaxf(mrow, vmax);
      float resc = __expf(mrow - mn);
      mrow = mn;
      lrow *= resc;
      #pragma unroll
      for (int dt = 0; dt < 16; ++dt)
        #pragma unroll
        for (int i = 0; i < 4; ++i) oacc[dt][i] *= resc;
    }
    // exp, sum, pack: quad n4 -> (Ln, Hn) u32 pairs
    float sum = 0.f;
    uint32_t L0, H0, L1, H1, L2, H2, L3, H3;
    {
      float e0, e1, e2, e3;
      e0 = __expf(sacc[0][0] - mrow); e1 = __expf(sacc[0][1] - mrow);
      e2 = __expf(sacc[0][2] - mrow); e3 = __expf(sacc[0][3] - mrow);
      sum += (e0 + e1) + (e2 + e3); L0 = pk2(e0, e1); H0 = pk2(e2, e3);
      e0 = __expf(sacc[1][0] - mrow); e1 = __expf(sacc[1][1] - mrow);
      e2 = __expf(sacc[1][2] - mrow); e3 = __expf(sacc[1][3] - mrow);
      sum += (e0 + e1) + (e2 + e3); L1 = pk2(e0, e1); H1 = pk2(e2, e3);
      e0 = __expf(sacc[2][0] - mrow); e1 = __expf(sacc[2][1] - mrow);
      e2 = __expf(sacc[2][2] - mrow); e3 = __expf(sacc[2][3] - mrow);
      sum += (e0 + e1) + (e2 + e3); L2 = pk2(e0, e1); H2 = pk2(e2, e3);
      e0 = __expf(sacc[3][0] - mrow); e1 = __expf(sacc[3][1] - mrow);
      e2 = __expf(sacc[3][2] - mrow); e3 = __expf(sacc[3][3] - mrow);
      sum += (e0 + e1) + (e2 + e3); L3 = pk2(e0, e1); H3 = pk2(e2, e3);
    }
    sum += __shfl_xor(sum, 16, 64);
    sum += __shfl_xor(sum, 32, 64);
    lrow += sum;

    // PV per s-half t2: O^T[d][q] += V^T[d][s] P[s][q].
    // B-frag(kg) = [L_Qn@2S, H_Qn@2S, L_Qn@(2S+1), H_Qn@(2S+1)],
    // Qn = kg>>1, S = kg&1; sources via butterfly {self, ^16, ^32, ^48}.
    const u16* Vd = Vs + buf * 16384;
    const int g = kg;
    #pragma unroll
    for (int t2 = 0; t2 < 2; ++t2) {
      uint32_t La = t2 ? L2 : L0, Ha = t2 ? H2 : H0;
      uint32_t Lb2 = t2 ? L3 : L1, Hb = t2 ? H3 : H1;
      uint32_t La1 = __shfl_xor(La, 16, 64), La2 = __shfl_xor(La, 32, 64);
      uint32_t La3 = __shfl_xor(La1, 32, 64);
      uint32_t Ha1 = __shfl_xor(Ha, 16, 64), Ha2 = __shfl_xor(Ha, 32, 64);
      uint32_t Ha3 = __shfl_xor(Ha1, 32, 64);
      uint32_t Lb1 = __shfl_xor(Lb2, 16, 64), Lb2s = __shfl_xor(Lb2, 32, 64);
      uint32_t Lb3 = __shfl_xor(Lb1, 32, 64);
      uint32_t Hb1 = __shfl_xor(Hb, 16, 64), Hb2 = __shfl_xor(Hb, 32, 64);
      uint32_t Hb3 = __shfl_xor(Hb1, 32, 64);
      // @2S: g0->self, g1->^48, g2->^32, g3->^16 ; @2S+1: g0->^16, g1->^32, g2->^48, g3->self
      uint32_t a2S  = (g == 0) ? La  : (g == 1) ? La3 : (g == 2) ? La2 : La1;
      uint32_t a2S1 = (g == 0) ? La1 : (g == 1) ? La2 : (g == 2) ? La3 : La;
      uint32_t ah2S  = (g == 0) ? Ha  : (g == 1) ? Ha3 : (g == 2) ? Ha2 : Ha1;
      uint32_t ah2S1 = (g == 0) ? Ha1 : (g == 1) ? Ha2 : (g == 2) ? Ha3 : Ha;
      uint32_t b2S  = (g == 0) ? Lb2 : (g == 1) ? Lb3 : (g == 2) ? Lb2s : Lb1;
      uint32_t b2S1 = (g == 0) ? Lb1 : (g == 1) ? Lb2s : (g == 2) ? Lb3 : Lb2;
      uint32_t bh2S  = (g == 0) ? Hb  : (g == 1) ? Hb3 : (g == 2) ? Hb2 : Hb1;
      uint32_t bh2S1 = (g == 0) ? Hb1 : (g == 1) ? Hb2 : (g == 2) ? Hb3 : Hb;
      const int Qn = g >> 1;
      union { uint32_t u[4]; bf16x8 v; } pf;
      pf.u[0] = Qn ? b2S  : a2S;
      pf.u[1] = Qn ? bh2S : ah2S;
      pf.u[2] = Qn ? b2S1 : a2S1;
      pf.u[3] = Qn ? bh2S1 : ah2S1;
      __builtin_amdgcn_s_setprio(1);
      #pragma unroll
      for (int dt = 0; dt < 16; ++dt) {
        int rv = dt * 16 + rr;
        int cv = t2 * 4 + kg;
        bf16x8 vf = *(const bf16x8*)&Vd[rv * 64 + ((cv ^ (rv & 7)) << 3)];
        oacc[dt] = MFMA16(vf, pf.v, oacc[dt]);
      }
      __builtin_amdgcn_s_setprio(0);
    }

    __syncthreads();  // drains vmcnt(0): next K/V staged; bufs safe to swap
    buf ^= 1;
  }

  // normalize + store: lane q=qrow, d = dt*16 + kg*4 + i
  float inv = 1.0f / lrow;
  #pragma unroll
  for (int dt = 0; dt < 16; ++dt) {
    union { u16 h4[4]; uint2 u2; } o4;
    #pragma unroll
    for (int i = 0; i < 4; ++i) o4.h4[i] = f2bf(oacc[dt][i] * inv);
    *(uint2*)&Ob[(size_t)qrow * 2048 + dt * 16 + kg * 4] = o4.u2;
  }
}

// ---------------------------------------------------------------------------
extern "C" void kernel_launch(void* const* d_in, const int* in_sizes, int n_in,
                              void* d_out, int out_size, void* d_ws, size_t ws_size,
                              hipStream_t stream) {
  const float* x  = (const float*)d_in[0];
  const float* Wq = (const float*)d_in[1];
  const float* Wk = (const float*)d_in[2];
  const float* Wv = (const float*)d_in[3];
  const float* Wu = (const float*)d_in[4];

  // workspace layout (u16 units)
  u16* xb  = (u16*)d_ws;                 // 8192*256
  u16* WtQ = xb  + 8192 * 256;           // 2048*256
  u16* WtK = WtQ + 2048 * 256;
  u16* WtV = WtK + 2048 * 256;
  u16* Wut = WtV + 2048 * 256;           // 256*2048
  u16* Qm  = Wut + 2048 * 256;           // 8192*2048 each below
  u16* Km  = Qm  + (size_t)8192 * 2048;
  u16* Vtm = Km  + (size_t)8192 * 2048;  // V written TRANSPOSED by gemm_bt<2>
  u16* Om  = Vtm + (size_t)8192 * 2048;

  const float inv4 = 0.25f;  // 256^(-1/4)

  cvt_bf16<<<2048, 256, 0, stream>>>(x, xb, 8192 * 256 / 4);
  transpose_cvt<<<dim3(64, 8), 256, 0, stream>>>(Wq, WtQ, 256, 2048, inv4);
  transpose_cvt<<<dim3(64, 8), 256, 0, stream>>>(Wk, WtK, 256, 2048, inv4);
  transpose_cvt<<<dim3(64, 8), 256, 0, stream>>>(Wv, WtV, 256, 2048, 1.0f);
  transpose_cvt<<<dim3(8, 64), 256, 0, stream>>>(Wu, Wut, 2048, 256, 1.0f);

  gemm_bt<0><<<dim3(16, 64), 256, 0, stream>>>(xb, WtQ, Qm, 8192, 2048, 256, 256, 256, 2048);
  gemm_bt<0><<<dim3(16, 64), 256, 0, stream>>>(xb, WtK, Km, 8192, 2048, 256, 256, 256, 2048);
  gemm_bt<2><<<dim3(16, 64), 256, 0, stream>>>(xb, WtV, Vtm, 8192, 2048, 256, 256, 256, 0);

  attn_kernel<<<512, 512, 0, stream>>>(Qm, Km, Vtm, Om);

  gemm_bt64<1><<<dim3(2, 128), 256, 0, stream>>>(Om, Wut, d_out, 8192, 256, 2048, 2048, 2048, 256);
}